// Round 9
// baseline (321.398 us; speedup 1.0000x reference)
//
#include <hip/hip_runtime.h>
#include <hip/hip_bf16.h>
#include <cstdint>

// ---------------------------------------------------------------------------
// TransducerJoint: out[b,t,u,:] = tanh(f[b,t,:] + g[b,u,:]) @ W_joint + b_joint
// R8 -> R9: fix the global_load_lds addressing bug (R7/R8 NaN root cause).
// HW rule (m104/m108): gload_lds LDS dest = wave-uniform base + lane*16;
// per-lane dest components are IGNORED. R8 used a per-thread dest (t*32).
// Fixed staging: wave w, instr s in {0,1} -> LDS dest = half + w*2048 + s*1024
// (uniform); lane l covers row r = w*16 + s*8 + (l>>3), source chunk
// c = (l&7) ^ (l>>3) (inverse of the slot^(r&7) XOR layout, r&7 == l>>3).
// Schedule (unchanged from R8, ledger re-verified):
//  * phase p reads exactly {A-half p>>1, B-half p&1}; wave decomp rg=w>>2
//    (64 rows/half), cg=w&3 (32 cols/half); one acc quadrant per phase
//  * tile kt stages ONLY tile kt+1 (other buffer), burst at p0, order
//    A0,B0,B1,A1
//  * counted vmcnt: prologue 4; steady p0:10, p1:8, p2:-, p3:4; tail 2,0
// ---------------------------------------------------------------------------

typedef __attribute__((ext_vector_type(4))) float f32x4;
typedef __attribute__((ext_vector_type(8))) short s16x8;

#define B_ 4
#define T_ 300
#define U_ 100
#define DM 512
#define VOC 1024
#define M_MAIN (B_*T_*U_)       // 120000
#define M_MAIN_PAD 120064       // 469 * 256
#define M_ENC_PAD 1280
#define M_PRED_PAD 512

__device__ __forceinline__ unsigned short f2bf(float x) {
  unsigned int u = __builtin_bit_cast(unsigned int, x);
  u += 0x7FFFu + ((u >> 16) & 1u);
  return (unsigned short)(u >> 16);
}

__device__ __forceinline__ float fast_tanh(float x) {
  float e = __builtin_amdgcn_exp2f(x * 2.8853900817779268f);
  return fmaf(-2.0f, __builtin_amdgcn_rcpf(e + 1.0f), 1.0f);
}

__device__ __forceinline__ void gload_lds16(const void* g, void* l) {
  __builtin_amdgcn_global_load_lds(
      (const __attribute__((address_space(1))) void*)g,
      (__attribute__((address_space(3))) void*)l, 16, 0, 0);
}

// ---------------------------------------------------------------------------
__global__ void k_cvtpad(const float* __restrict__ enc, const float* __restrict__ pred,
                         unsigned short* __restrict__ encb, unsigned short* __restrict__ predb)
{
  int idx = blockIdx.x * 256 + threadIdx.x;
  const int encCh = M_ENC_PAD * 64;
  const float* src; unsigned short* dst; int Mv; int id2;
  if (idx < encCh) { src = enc; dst = encb; Mv = B_*T_; id2 = idx; }
  else            { id2 = idx - encCh; src = pred; dst = predb; Mv = B_*U_; }
  int r = id2 >> 6, k = (id2 & 63) * 8;
  s16x8 v;
  if (r < Mv) {
    f32x4 a = *(const f32x4*)(src + r*DM + k);
    f32x4 b = *(const f32x4*)(src + r*DM + k + 4);
#pragma unroll
    for (int j = 0; j < 4; ++j) { v[j] = (short)f2bf(a[j]); v[4+j] = (short)f2bf(b[j]); }
  } else {
#pragma unroll
    for (int j = 0; j < 8; ++j) v[j] = 0;
  }
  *(s16x8*)(dst + (long)id2 * 8) = v;
}

// ---------------------------------------------------------------------------
__global__ void k_transpose3(const float* __restrict__ We, const float* __restrict__ Wp,
                             const float* __restrict__ Wj,
                             unsigned short* __restrict__ WeT, unsigned short* __restrict__ WpT,
                             unsigned short* __restrict__ WjT)
{
  __shared__ float tile[32][33];
  const float* src; unsigned short* dst; int Ccols;
  const int R = 512;
  if (blockIdx.z == 0)      { src = We; dst = WeT; Ccols = 512; }
  else if (blockIdx.z == 1) { src = Wp; dst = WpT; Ccols = 512; }
  else                      { src = Wj; dst = WjT; Ccols = 1024; }
  int bx = blockIdx.x, by = blockIdx.y;
  if (bx * 32 >= Ccols) return;
  int x = threadIdx.x & 31, y = threadIdx.x >> 5;
  int c0 = bx * 32, r0 = by * 32;
#pragma unroll
  for (int i = 0; i < 4; ++i)
    tile[y + i*8][x] = src[(r0 + y + i*8) * Ccols + c0 + x];
  __syncthreads();
#pragma unroll
  for (int i = 0; i < 4; ++i)
    dst[(c0 + y + i*8) * R + r0 + x] = f2bf(tile[x][y + i*8]);
}

// ---------------------------------------------------------------------------
// 128x128 gemm body (small f/g GEMMs only).
// ---------------------------------------------------------------------------
__device__ __forceinline__ void gemm_body(const unsigned short* __restrict__ A,
                                          const unsigned short* __restrict__ Bt,
                                          const float* __restrict__ bias,
                                          float* __restrict__ C,
                                          int Mvalid, int ldc, int mt, int nt)
{
  __shared__ unsigned short lza[128*64];
  __shared__ unsigned short lzb[128*64];
  const int tid  = threadIdx.x;
  const int wave = tid >> 6;
  const int lane = tid & 63;
  const int row0 = mt * 128;
  const int col0 = nt * 128;
  const int wm = (wave >> 1) * 64;
  const int wn = (wave & 1) * 64;

  const int rloc0 = wave*32 + (lane >> 3);
  const int srcc  = (lane & 7) ^ (rloc0 & 7);
  const unsigned short* gA = A  + (row0 + rloc0)*DM + srcc*8;
  const unsigned short* gB = Bt + (col0 + rloc0)*DM + srcc*8;
  unsigned short* ldsA = &lza[(wave*32)*64];
  unsigned short* ldsB = &lzb[(wave*32)*64];

  f32x4 acc[4][4] = {};

  for (int kt = 0; kt < DM/64; ++kt) {
    __syncthreads();
#pragma unroll
    for (int i = 0; i < 4; ++i) {
      gload_lds16(gA + i*8*DM, ldsA + i*8*64);
      gload_lds16(gB + i*8*DM, ldsB + i*8*64);
    }
    gA += 64; gB += 64;
    __syncthreads();
#pragma unroll
    for (int kk = 0; kk < 2; ++kk) {
      s16x8 af[4], bfr[4];
#pragma unroll
      for (int m = 0; m < 4; ++m) {
        int r = wm + m*16 + (lane & 15);
        int c = (kk*4 + (lane >> 4)) ^ (r & 7);
        af[m] = *(const s16x8*)&lza[r*64 + c*8];
      }
#pragma unroll
      for (int n = 0; n < 4; ++n) {
        int r = wn + n*16 + (lane & 15);
        int c = (kk*4 + (lane >> 4)) ^ (r & 7);
        bfr[n] = *(const s16x8*)&lzb[r*64 + c*8];
      }
#pragma unroll
      for (int m = 0; m < 4; ++m)
#pragma unroll
        for (int n = 0; n < 4; ++n)
          acc[m][n] = __builtin_amdgcn_mfma_f32_16x16x32_bf16(af[m], bfr[n], acc[m][n], 0, 0, 0);
    }
  }

  const int cl = lane & 15, rq = (lane >> 4) * 4;
#pragma unroll
  for (int n = 0; n < 4; ++n) {
    int col = col0 + wn + n*16 + cl;
    float bv = bias[col];
#pragma unroll
    for (int m = 0; m < 4; ++m) {
      int rb = row0 + wm + m*16 + rq;
#pragma unroll
      for (int j = 0; j < 4; ++j) {
        int r = rb + j;
        if (r < Mvalid) __builtin_nontemporal_store(acc[m][n][j] + bv, &C[(long)r * ldc + col]);
      }
    }
  }
}

__global__ __launch_bounds__(256, 2) void k_gemm_fg(
    const unsigned short* __restrict__ encb,  const unsigned short* __restrict__ WeT,
    const float* __restrict__ b_enc,  float* __restrict__ f,
    const unsigned short* __restrict__ predb, const unsigned short* __restrict__ WpT,
    const float* __restrict__ b_pred, float* __restrict__ g)
{
  const unsigned short* A;  const unsigned short* Bt;
  const float* bias; float* C; int Mv;
  if (blockIdx.z == 0) { A = encb;  Bt = WeT; bias = b_enc;  C = f; Mv = M_ENC_PAD; }
  else {
    if (blockIdx.x >= M_PRED_PAD/128) return;
    A = predb; Bt = WpT; bias = b_pred; C = g; Mv = M_PRED_PAD;
  }
  gemm_body(A, Bt, bias, C, Mv, DM, blockIdx.x, blockIdx.y);
}

// ---------------------------------------------------------------------------
__global__ void k_build_a(const float* __restrict__ f, const float* __restrict__ g,
                          unsigned short* __restrict__ Abuf)
{
  int idx = blockIdx.x * 256 + threadIdx.x;
  int r = idx >> 6;
  int k = (idx & 63) * 8;
  s16x8 v;
  if (r < M_MAIN) {
    int b   = r / (T_*U_);
    int rem = r - b * (T_*U_);
    int t   = rem / U_;
    int u   = rem - t * U_;
    const float* fr = f + (b*T_ + t) * DM + k;
    const float* gr = g + (b*U_ + u) * DM + k;
    f32x4 f0 = *(const f32x4*)fr;
    f32x4 f1 = *(const f32x4*)(fr + 4);
    f32x4 g0 = *(const f32x4*)gr;
    f32x4 g1 = *(const f32x4*)(gr + 4);
#pragma unroll
    for (int j = 0; j < 4; ++j) {
      v[j]   = (short)f2bf(fast_tanh(f0[j] + g0[j]));
      v[4+j] = (short)f2bf(fast_tanh(f1[j] + g1[j]));
    }
  } else {
#pragma unroll
    for (int j = 0; j < 8; ++j) v[j] = 0;
  }
  *(s16x8*)(Abuf + (long)idx * 8) = v;
}

// ---------------------------------------------------------------------------
// Main GEMM, 8-phase 256x256, ledger-correct, HW-correct staging.
// LDS: A[buf][half] at buf*32768 + half*16384; B at 65536 + same. 128 KB.
// Layout per 16KB half: row r (128B), slot s holds global chunk s^(r&7).
// Staging realizes it: wave w instr s writes rows w*16+s*8..+7 linearly
// (lane l -> row +(l>>3), slot l&7) from source chunk (l&7)^(l>>3).
// ---------------------------------------------------------------------------
__global__ __launch_bounds__(512, 2) void k_gemm_8p(
    const unsigned short* __restrict__ A, const unsigned short* __restrict__ Bt,
    const float* __restrict__ bias, float* __restrict__ C)
{
  __shared__ unsigned short lds[65536];   // 128 KB
  char* ldsb = (char*)lds;

  const int bid = blockIdx.x;
  const int mt = bid >> 2, nt = bid & 3;          // n-fastest: A-panel reuse
  const long row0 = (long)mt * 256;
  const int col0 = nt * 256;
  const int t = threadIdx.x, w = t >> 6, l = t & 63;
  const int rg = w >> 2;                          // 64-row group within each A-half
  const int cg = w & 3;                           // 32-col group within each B-half
  const int lr = l & 15, lc = l >> 4;

  // ---- staging (HW-correct): wave-uniform LDS dest, per-lane global src ----
  const int sr0 = w*16 + (l >> 3);                // row covered at s=0
  const int sr1 = sr0 + 8;                        // row covered at s=1
  const int sc  = (l & 7) ^ (l >> 3);             // source chunk (r&7 == l>>3)
  // gp[ty][s]: ty 0=A0, 1=B0, 2=B1, 3=A1
  const unsigned short* gp[4][2];
  gp[0][0] = A  + (row0 +       sr0) * DM + sc*8;
  gp[0][1] = A  + (row0 +       sr1) * DM + sc*8;
  gp[3][0] = A  + (row0 + 128 + sr0) * DM + sc*8;
  gp[3][1] = A  + (row0 + 128 + sr1) * DM + sc*8;
  gp[1][0] = Bt + (long)(col0 +       sr0) * DM + sc*8;
  gp[1][1] = Bt + (long)(col0 +       sr1) * DM + sc*8;
  gp[2][0] = Bt + (long)(col0 + 128 + sr0) * DM + sc*8;
  gp[2][1] = Bt + (long)(col0 + 128 + sr1) * DM + sc*8;
  const int wbase = w * 2048;                     // uniform byte base in a half

  // ---- fragment read offsets (bytes within a 16KB half): slot=(kk*4+lc)^(r&7)
  int offA[4][2], offB[2][2];
#pragma unroll
  for (int q = 0; q < 4; ++q) {
    int r = rg*64 + q*16 + lr;
#pragma unroll
    for (int kk = 0; kk < 2; ++kk)
      offA[q][kk] = r*128 + (((kk*4 + lc) ^ (r & 7))*16);
  }
#pragma unroll
  for (int j = 0; j < 2; ++j) {
    int r = cg*32 + j*16 + lr;
#pragma unroll
    for (int kk = 0; kk < 2; ++kk)
      offB[j][kk] = r*128 + (((kk*4 + lc) ^ (r & 7))*16);
  }

  // stage half ty of a tile (ty_ is always a literal -> static gp indexing)
#define DO_STAGE(tile_, ty_) { \
    const int dbase = (((ty_)==0 || (ty_)==3) ? 0 : 65536) + ((tile_)&1)*32768 \
                      + (((ty_)>=2) ? 16384 : 0) + wbase; \
    gload_lds16(gp[(ty_)][0] + (tile_)*64, ldsb + dbase); \
    gload_lds16(gp[(ty_)][1] + (tile_)*64, ldsb + dbase + 1024); }

#define PHASE(kt_, p_) { \
    const int mp = (p_) >> 1, np = (p_) & 1; \
    const int bufo = ((kt_) & 1) * 32768; \
    if ((p_) == 0 && (kt_) < 7) { \
      DO_STAGE((kt_)+1, 0); DO_STAGE((kt_)+1, 1); DO_STAGE((kt_)+1, 2); DO_STAGE((kt_)+1, 3); } \
    s16x8 aq[4][2], bq[2][2]; \
    _Pragma("unroll") \
    for (int q = 0; q < 4; ++q) \
      _Pragma("unroll") \
      for (int kk = 0; kk < 2; ++kk) \
        aq[q][kk] = *(const s16x8*)(ldsb + bufo + mp*16384 + offA[q][kk]); \
    _Pragma("unroll") \
    for (int j = 0; j < 2; ++j) \
      _Pragma("unroll") \
      for (int kk = 0; kk < 2; ++kk) \
        bq[j][kk] = *(const s16x8*)(ldsb + 65536 + bufo + np*16384 + offB[j][kk]); \
    if ((kt_) < 7) { \
      if ((p_) == 0)      asm volatile("s_waitcnt vmcnt(10)" ::: "memory"); \
      else if ((p_) == 1) asm volatile("s_waitcnt vmcnt(8)"  ::: "memory"); \
      else if ((p_) == 3) asm volatile("s_waitcnt vmcnt(4)"  ::: "memory"); \
    } else { \
      if ((p_) == 0)      asm volatile("s_waitcnt vmcnt(2)"  ::: "memory"); \
      else if ((p_) == 1) asm volatile("s_waitcnt vmcnt(0)"  ::: "memory"); \
    } \
    __builtin_amdgcn_s_barrier(); \
    asm volatile("s_waitcnt lgkmcnt(0)" ::: "memory"); \
    __builtin_amdgcn_sched_barrier(0); \
    __builtin_amdgcn_s_setprio(1); \
    _Pragma("unroll") \
    for (int q = 0; q < 4; ++q) \
      _Pragma("unroll") \
      for (int j = 0; j < 2; ++j) \
        _Pragma("unroll") \
        for (int kk = 0; kk < 2; ++kk) \
          acc[mp*4+q][np*2+j] = __builtin_amdgcn_mfma_f32_16x16x32_bf16( \
              aq[q][kk], bq[j][kk], acc[mp*4+q][np*2+j], 0, 0, 0); \
    __builtin_amdgcn_s_setprio(0); \
    __builtin_amdgcn_s_barrier(); }

  f32x4 acc[8][4] = {};

  // ---- prologue: tile 0, halves A0,B0,B1,A1; need A0,B0 before (0,0) ----
  DO_STAGE(0, 0); DO_STAGE(0, 1); DO_STAGE(0, 2); DO_STAGE(0, 3);
  asm volatile("s_waitcnt vmcnt(4)" ::: "memory");
  __builtin_amdgcn_s_barrier();

  // ---- 8 K-tiles x 4 phases ----
#pragma unroll
  for (int kt = 0; kt < 8; ++kt) {
    PHASE(kt, 0); PHASE(kt, 1); PHASE(kt, 2); PHASE(kt, 3);
  }

  // ---- epilogue: frag row = base_m + lc*4 + jj, col = base_n + lr ----
  const int rq = lc * 4;
#pragma unroll
  for (int n = 0; n < 4; ++n) {
    const int np = n >> 1, j = n & 1;
    int col = col0 + np*128 + cg*32 + j*16 + lr;
    float bv = bias[col];
#pragma unroll
    for (int m = 0; m < 8; ++m) {
      const int mp = m >> 2, q = m & 3;
      long rb = row0 + mp*128 + rg*64 + q*16 + rq;
#pragma unroll
      for (int jj = 0; jj < 4; ++jj) {
        long r = rb + jj;
        if (r < M_MAIN)
          __builtin_nontemporal_store(acc[m][n][jj] + bv, &C[r * VOC + col]);
      }
    }
  }
#undef DO_STAGE
#undef PHASE
}

// ---------------------------------------------------------------------------
extern "C" void kernel_launch(void* const* d_in, const int* in_sizes, int n_in,
                              void* d_out, int out_size, void* d_ws, size_t ws_size,
                              hipStream_t stream)
{
  const float* enc    = (const float*)d_in[0];
  const float* pred   = (const float*)d_in[1];
  const float* W_enc  = (const float*)d_in[2];
  const float* b_enc  = (const float*)d_in[3];
  const float* W_pred = (const float*)d_in[4];
  const float* b_pred = (const float*)d_in[5];
  const float* W_joint= (const float*)d_in[6];
  const float* b_joint= (const float*)d_in[7];
  float* out = (float*)d_out;

  char* w = (char*)d_ws;
  unsigned short* encb  = (unsigned short*)w; w += (long)M_ENC_PAD*DM*2;
  unsigned short* predb = (unsigned short*)w; w += (long)M_PRED_PAD*DM*2;
  unsigned short* WeT   = (unsigned short*)w; w += (long)DM*DM*2;
  unsigned short* WpT   = (unsigned short*)w; w += (long)DM*DM*2;
  unsigned short* WjT   = (unsigned short*)w; w += (long)VOC*DM*2;
  float*          f     = (float*)w;          w += (long)M_ENC_PAD*DM*4;
  float*          g     = (float*)w;          w += (long)M_PRED_PAD*DM*4;
  unsigned short* Abuf  = (unsigned short*)w; w += (long)M_MAIN_PAD*DM*2;

  k_cvtpad    <<<dim3(448),        dim3(256), 0, stream>>>(enc, pred, encb, predb);
  k_transpose3<<<dim3(32, 16, 3),  dim3(256), 0, stream>>>(W_enc, W_pred, W_joint, WeT, WpT, WjT);
  k_gemm_fg   <<<dim3(10, 4, 2),   dim3(256), 0, stream>>>(encb, WeT, b_enc, f, predb, WpT, b_pred, g);
  k_build_a   <<<dim3((M_MAIN_PAD*64)/256), dim3(256), 0, stream>>>(f, g, Abuf);
  k_gemm_8p   <<<dim3(469*4),      dim3(512), 0, stream>>>(Abuf, WjT, b_joint, out);
}

// Round 10
// 295.001 us; speedup vs baseline: 1.0895x; 1.0895x over previous
//
#include <hip/hip_runtime.h>
#include <hip/hip_bf16.h>
#include <cstdint>

// ---------------------------------------------------------------------------
// TransducerJoint: out[b,t,u,:] = tanh(f[b,t,:] + g[b,u,:]) @ W_joint + b_joint
// R9 -> R10: main GEMM = minimum-2-phase counted schedule on the 128x128
// geometry (catalog: ~92% of 8-phase, and our 8-phase double-read quadrant
// scheme was LDS-bound):
//  * per K-tile: issue STAGE(kt+1 -> other buf) FIRST, then 16 ds_read_b128
//    frags(kt), 32 MFMA (setprio), ONE __syncthreads (its vmcnt0+lgkm0 drain
//    IS the ledger for distance-1 prefetch; latency hides under ~450cyc body)
//  * double-buffered 64 KB LDS -> 2 blocks/CU (cross-block overlap of
//    prologue/epilogue, m114)
//  * XCD-co-locating swizzle: all 8 n-tiles of an A-panel get bid = xcd mod 8
//    (bijective uneven split of 938 panel groups over 8 XCDs, 48 pad blocks)
//    -> panel fetched once per L2 (R9 FETCH 248 MB -> ~140)
//  * staging/read XOR-8 slot layout byte-identical to R9 (verified 0 bank
//    conflicts), wave-uniform gload_lds dest (HW rule m104/m108)
// ---------------------------------------------------------------------------

typedef __attribute__((ext_vector_type(4))) float f32x4;
typedef __attribute__((ext_vector_type(8))) short s16x8;

#define B_ 4
#define T_ 300
#define U_ 100
#define DM 512
#define VOC 1024
#define M_MAIN (B_*T_*U_)       // 120000
#define M_MAIN_PAD 120064       // 938 * 128
#define M_ENC_PAD 1280
#define M_PRED_PAD 512

__device__ __forceinline__ unsigned short f2bf(float x) {
  unsigned int u = __builtin_bit_cast(unsigned int, x);
  u += 0x7FFFu + ((u >> 16) & 1u);
  return (unsigned short)(u >> 16);
}

__device__ __forceinline__ float fast_tanh(float x) {
  float e = __builtin_amdgcn_exp2f(x * 2.8853900817779268f);
  return fmaf(-2.0f, __builtin_amdgcn_rcpf(e + 1.0f), 1.0f);
}

__device__ __forceinline__ void gload_lds16(const void* g, void* l) {
  __builtin_amdgcn_global_load_lds(
      (const __attribute__((address_space(1))) void*)g,
      (__attribute__((address_space(3))) void*)l, 16, 0, 0);
}

// ---------------------------------------------------------------------------
__global__ void k_cvtpad(const float* __restrict__ enc, const float* __restrict__ pred,
                         unsigned short* __restrict__ encb, unsigned short* __restrict__ predb)
{
  int idx = blockIdx.x * 256 + threadIdx.x;
  const int encCh = M_ENC_PAD * 64;
  const float* src; unsigned short* dst; int Mv; int id2;
  if (idx < encCh) { src = enc; dst = encb; Mv = B_*T_; id2 = idx; }
  else            { id2 = idx - encCh; src = pred; dst = predb; Mv = B_*U_; }
  int r = id2 >> 6, k = (id2 & 63) * 8;
  s16x8 v;
  if (r < Mv) {
    f32x4 a = *(const f32x4*)(src + r*DM + k);
    f32x4 b = *(const f32x4*)(src + r*DM + k + 4);
#pragma unroll
    for (int j = 0; j < 4; ++j) { v[j] = (short)f2bf(a[j]); v[4+j] = (short)f2bf(b[j]); }
  } else {
#pragma unroll
    for (int j = 0; j < 8; ++j) v[j] = 0;
  }
  *(s16x8*)(dst + (long)id2 * 8) = v;
}

// ---------------------------------------------------------------------------
__global__ void k_transpose3(const float* __restrict__ We, const float* __restrict__ Wp,
                             const float* __restrict__ Wj,
                             unsigned short* __restrict__ WeT, unsigned short* __restrict__ WpT,
                             unsigned short* __restrict__ WjT)
{
  __shared__ float tile[32][33];
  const float* src; unsigned short* dst; int Ccols;
  const int R = 512;
  if (blockIdx.z == 0)      { src = We; dst = WeT; Ccols = 512; }
  else if (blockIdx.z == 1) { src = Wp; dst = WpT; Ccols = 512; }
  else                      { src = Wj; dst = WjT; Ccols = 1024; }
  int bx = blockIdx.x, by = blockIdx.y;
  if (bx * 32 >= Ccols) return;
  int x = threadIdx.x & 31, y = threadIdx.x >> 5;
  int c0 = bx * 32, r0 = by * 32;
#pragma unroll
  for (int i = 0; i < 4; ++i)
    tile[y + i*8][x] = src[(r0 + y + i*8) * Ccols + c0 + x];
  __syncthreads();
#pragma unroll
  for (int i = 0; i < 4; ++i)
    dst[(c0 + y + i*8) * R + r0 + x] = f2bf(tile[x][y + i*8]);
}

// ---------------------------------------------------------------------------
// 128x128 gemm body (small f/g GEMMs only).
// ---------------------------------------------------------------------------
__device__ __forceinline__ void gemm_body(const unsigned short* __restrict__ A,
                                          const unsigned short* __restrict__ Bt,
                                          const float* __restrict__ bias,
                                          float* __restrict__ C,
                                          int Mvalid, int ldc, int mt, int nt)
{
  __shared__ unsigned short lza[128*64];
  __shared__ unsigned short lzb[128*64];
  const int tid  = threadIdx.x;
  const int wave = tid >> 6;
  const int lane = tid & 63;
  const int row0 = mt * 128;
  const int col0 = nt * 128;
  const int wm = (wave >> 1) * 64;
  const int wn = (wave & 1) * 64;

  const int rloc0 = wave*32 + (lane >> 3);
  const int srcc  = (lane & 7) ^ (rloc0 & 7);
  const unsigned short* gA = A  + (row0 + rloc0)*DM + srcc*8;
  const unsigned short* gB = Bt + (col0 + rloc0)*DM + srcc*8;
  unsigned short* ldsA = &lza[(wave*32)*64];
  unsigned short* ldsB = &lzb[(wave*32)*64];

  f32x4 acc[4][4] = {};

  for (int kt = 0; kt < DM/64; ++kt) {
    __syncthreads();
#pragma unroll
    for (int i = 0; i < 4; ++i) {
      gload_lds16(gA + i*8*DM, ldsA + i*8*64);
      gload_lds16(gB + i*8*DM, ldsB + i*8*64);
    }
    gA += 64; gB += 64;
    __syncthreads();
#pragma unroll
    for (int kk = 0; kk < 2; ++kk) {
      s16x8 af[4], bfr[4];
#pragma unroll
      for (int m = 0; m < 4; ++m) {
        int r = wm + m*16 + (lane & 15);
        int c = (kk*4 + (lane >> 4)) ^ (r & 7);
        af[m] = *(const s16x8*)&lza[r*64 + c*8];
      }
#pragma unroll
      for (int n = 0; n < 4; ++n) {
        int r = wn + n*16 + (lane & 15);
        int c = (kk*4 + (lane >> 4)) ^ (r & 7);
        bfr[n] = *(const s16x8*)&lzb[r*64 + c*8];
      }
#pragma unroll
      for (int m = 0; m < 4; ++m)
#pragma unroll
        for (int n = 0; n < 4; ++n)
          acc[m][n] = __builtin_amdgcn_mfma_f32_16x16x32_bf16(af[m], bfr[n], acc[m][n], 0, 0, 0);
    }
  }

  const int cl = lane & 15, rq = (lane >> 4) * 4;
#pragma unroll
  for (int n = 0; n < 4; ++n) {
    int col = col0 + wn + n*16 + cl;
    float bv = bias[col];
#pragma unroll
    for (int m = 0; m < 4; ++m) {
      int rb = row0 + wm + m*16 + rq;
#pragma unroll
      for (int j = 0; j < 4; ++j) {
        int r = rb + j;
        if (r < Mvalid) __builtin_nontemporal_store(acc[m][n][j] + bv, &C[(long)r * ldc + col]);
      }
    }
  }
}

__global__ __launch_bounds__(256, 2) void k_gemm_fg(
    const unsigned short* __restrict__ encb,  const unsigned short* __restrict__ WeT,
    const float* __restrict__ b_enc,  float* __restrict__ f,
    const unsigned short* __restrict__ predb, const unsigned short* __restrict__ WpT,
    const float* __restrict__ b_pred, float* __restrict__ g)
{
  const unsigned short* A;  const unsigned short* Bt;
  const float* bias; float* C; int Mv;
  if (blockIdx.z == 0) { A = encb;  Bt = WeT; bias = b_enc;  C = f; Mv = M_ENC_PAD; }
  else {
    if (blockIdx.x >= M_PRED_PAD/128) return;
    A = predb; Bt = WpT; bias = b_pred; C = g; Mv = M_PRED_PAD;
  }
  gemm_body(A, Bt, bias, C, Mv, DM, blockIdx.x, blockIdx.y);
}

// ---------------------------------------------------------------------------
__global__ void k_build_a(const float* __restrict__ f, const float* __restrict__ g,
                          unsigned short* __restrict__ Abuf)
{
  int idx = blockIdx.x * 256 + threadIdx.x;
  int r = idx >> 6;
  int k = (idx & 63) * 8;
  s16x8 v;
  if (r < M_MAIN) {
    int b   = r / (T_*U_);
    int rem = r - b * (T_*U_);
    int t   = rem / U_;
    int u   = rem - t * U_;
    const float* fr = f + (b*T_ + t) * DM + k;
    const float* gr = g + (b*U_ + u) * DM + k;
    f32x4 f0 = *(const f32x4*)fr;
    f32x4 f1 = *(const f32x4*)(fr + 4);
    f32x4 g0 = *(const f32x4*)gr;
    f32x4 g1 = *(const f32x4*)(gr + 4);
#pragma unroll
    for (int j = 0; j < 4; ++j) {
      v[j]   = (short)f2bf(fast_tanh(f0[j] + g0[j]));
      v[4+j] = (short)f2bf(fast_tanh(f1[j] + g1[j]));
    }
  } else {
#pragma unroll
    for (int j = 0; j < 8; ++j) v[j] = 0;
  }
  *(s16x8*)(Abuf + (long)idx * 8) = v;
}

// ---------------------------------------------------------------------------
// Main GEMM: 128x128 tile, BK=64, 4 waves, double-buffered 64 KB LDS,
// 2 blocks/CU, minimum-2-phase counted schedule, XCD-co-locating swizzle.
// LDS byte map: buf b at b*32768: [A 16384 | B 16384]. Row r = 128 B;
// slot s (16B) holds global chunk s^(r&7).
// Staging: instr s in 0..3, wave w -> uniform dest s*4096 + w*1024; lane l
// covers row s*32 + w*8 + (l>>3), slot l&7, source chunk (l&7)^(l>>3).
// ---------------------------------------------------------------------------
__global__ __launch_bounds__(256, 2) void k_gemm_2p(
    const unsigned short* __restrict__ A, const unsigned short* __restrict__ Bt,
    const float* __restrict__ bias, float* __restrict__ C)
{
  __shared__ unsigned short lds[32768];   // 64 KB
  char* ldsb = (char*)lds;

  // ---- XCD-co-locating bijective decode (938 panel groups over 8 XCDs) ----
  const int bid = blockIdx.x;             // 0..7551 (48 pad blocks no-op)
  const int x = bid & 7;                  // XCD class (round-robin by bid%8)
  const int kq = bid >> 3;
  const int ip = kq >> 3;                 // group slot within this XCD
  const int nt = kq & 7;                  // n-tile (8 per panel, same XCD)
  const int cnt = (x < 2) ? 118 : 117;    // 938 = 2*118 + 6*117
  if (ip >= cnt) return;
  const int mt = (x < 2) ? x*118 + ip : 236 + (x - 2)*117 + ip;
  const long row0 = (long)mt * 128;
  const int col0 = nt * 128;

  const int t = threadIdx.x, w = t >> 6, l = t & 63;
  const int wm = w >> 1, wn = w & 1, lr = l & 15, lc = l >> 4;

  // ---- staging pointers (per-lane global src, wave-uniform LDS dest) ----
  const int srl = w*8 + (l >> 3);
  const int sc  = (l & 7) ^ (l >> 3);
  const unsigned short* pA = A  + (row0 + srl) * DM + sc*8;
  const unsigned short* pB = Bt + (long)(col0 + srl) * DM + sc*8;
  const int wbase = w * 1024;

#define STAGE(kt_, b_) { \
    _Pragma("unroll") \
    for (int s = 0; s < 4; ++s) \
      gload_lds16(pA + (long)s*32*DM + (kt_)*64, ldsb + (b_)*32768 + s*4096 + wbase); \
    _Pragma("unroll") \
    for (int s = 0; s < 4; ++s) \
      gload_lds16(pB + (long)s*32*DM + (kt_)*64, ldsb + (b_)*32768 + 16384 + s*4096 + wbase); }

  // ---- fragment read offsets (bytes within a 16 KB tile) ----
  int offA[4][2], offB[4][2];
#pragma unroll
  for (int m = 0; m < 4; ++m) {
    int r = wm*64 + m*16 + lr;
#pragma unroll
    for (int kk = 0; kk < 2; ++kk)
      offA[m][kk] = r*128 + (((kk*4 + lc) ^ (r & 7))*16);
  }
#pragma unroll
  for (int n = 0; n < 4; ++n) {
    int r = wn*64 + n*16 + lr;
#pragma unroll
    for (int kk = 0; kk < 2; ++kk)
      offB[n][kk] = r*128 + (((kk*4 + lc) ^ (r & 7))*16);
  }

  f32x4 acc[4][4] = {};

  // ---- prologue: tiles 0,1 in flight; wait only tile 0 (counted) ----
  STAGE(0, 0); STAGE(1, 1);
  asm volatile("s_waitcnt vmcnt(8)" ::: "memory");
  __builtin_amdgcn_s_barrier();

  // ---- 8 K-tiles, minimum-2-phase ----
#pragma unroll
  for (int kt = 0; kt < 8; ++kt) {
    const int cur = kt & 1;
    if (kt >= 1 && kt < 7) STAGE(kt + 1, cur ^ 1);   // issue-early (T14 shape)

    s16x8 af[4][2], bf[4][2];
#pragma unroll
    for (int m = 0; m < 4; ++m)
#pragma unroll
      for (int kk = 0; kk < 2; ++kk)
        af[m][kk] = *(const s16x8*)(ldsb + cur*32768 + offA[m][kk]);
#pragma unroll
    for (int n = 0; n < 4; ++n)
#pragma unroll
      for (int kk = 0; kk < 2; ++kk)
        bf[n][kk] = *(const s16x8*)(ldsb + cur*32768 + 16384 + offB[n][kk]);

    __builtin_amdgcn_s_setprio(1);
#pragma unroll
    for (int m = 0; m < 4; ++m)
#pragma unroll
      for (int n = 0; n < 4; ++n)
#pragma unroll
        for (int kk = 0; kk < 2; ++kk)
          acc[m][n] = __builtin_amdgcn_mfma_f32_16x16x32_bf16(
              af[m][kk], bf[n][kk], acc[m][n], 0, 0, 0);
    __builtin_amdgcn_s_setprio(0);

    if (kt < 7) __syncthreads();   // drain = exactly the distance-1 ledger
  }

  // ---- epilogue: C/D layout col=lane&15, row=(lane>>4)*4+jj ----
  const int rq = lc * 4;
#pragma unroll
  for (int n = 0; n < 4; ++n) {
    int col = col0 + wn*64 + n*16 + lr;
    float bv = bias[col];
#pragma unroll
    for (int m = 0; m < 4; ++m) {
      long rb = row0 + wm*64 + m*16 + rq;
#pragma unroll
      for (int jj = 0; jj < 4; ++jj) {
        long r = rb + jj;
        if (r < M_MAIN)
          __builtin_nontemporal_store(acc[m][n][jj] + bv, &C[r * VOC + col]);
      }
    }
  }
#undef STAGE
}

// ---------------------------------------------------------------------------
extern "C" void kernel_launch(void* const* d_in, const int* in_sizes, int n_in,
                              void* d_out, int out_size, void* d_ws, size_t ws_size,
                              hipStream_t stream)
{
  const float* enc    = (const float*)d_in[0];
  const float* pred   = (const float*)d_in[1];
  const float* W_enc  = (const float*)d_in[2];
  const float* b_enc  = (const float*)d_in[3];
  const float* W_pred = (const float*)d_in[4];
  const float* b_pred = (const float*)d_in[5];
  const float* W_joint= (const float*)d_in[6];
  const float* b_joint= (const float*)d_in[7];
  float* out = (float*)d_out;

  char* w = (char*)d_ws;
  unsigned short* encb  = (unsigned short*)w; w += (long)M_ENC_PAD*DM*2;
  unsigned short* predb = (unsigned short*)w; w += (long)M_PRED_PAD*DM*2;
  unsigned short* WeT   = (unsigned short*)w; w += (long)DM*DM*2;
  unsigned short* WpT   = (unsigned short*)w; w += (long)DM*DM*2;
  unsigned short* WjT   = (unsigned short*)w; w += (long)VOC*DM*2;
  float*          f     = (float*)w;          w += (long)M_ENC_PAD*DM*4;
  float*          g     = (float*)w;          w += (long)M_PRED_PAD*DM*4;
  unsigned short* Abuf  = (unsigned short*)w; w += (long)M_MAIN_PAD*DM*2;

  k_cvtpad    <<<dim3(448),        dim3(256), 0, stream>>>(enc, pred, encb, predb);
  k_transpose3<<<dim3(32, 16, 3),  dim3(256), 0, stream>>>(W_enc, W_pred, W_joint, WeT, WpT, WjT);
  k_gemm_fg   <<<dim3(10, 4, 2),   dim3(256), 0, stream>>>(encb, WeT, b_enc, f, predb, WpT, b_pred, g);
  k_build_a   <<<dim3((M_MAIN_PAD*64)/256), dim3(256), 0, stream>>>(f, g, Abuf);
  k_gemm_2p   <<<dim3(944*8),      dim3(256), 0, stream>>>(Abuf, WjT, b_joint, out);
}